// Round 12
// baseline (36624.518 us; speedup 1.0000x reference)
//
#include <hip/hip_runtime.h>
#include <stdint.h>
#include <stddef.h>

#define T_STEPS 32768
#define HDIM    256

__device__ __forceinline__ float sigmoidf_(float x) {
    return 1.0f / (1.0f + __expf(-x));
}
__device__ __forceinline__ float tanhf_(float x) {
    float e2 = __expf(2.0f * x);
    return 1.0f - 2.0f / (e2 + 1.0f);
}
// uniform value -> SGPR
__device__ __forceinline__ float rfl_(float x) {
    return __builtin_bit_cast(float, __builtin_amdgcn_readfirstlane(__builtin_bit_cast(int, x)));
}

__device__ __forceinline__ int sdot4_(uint32_t a, uint32_t b, int c) {
#if defined(__has_builtin) && __has_builtin(__builtin_amdgcn_sdot4)
    return __builtin_amdgcn_sdot4((int)a, (int)b, c, false);
#else
    int d;
    asm("v_dot4_i32_i8 %0, %1, %2, %3" : "=v"(d) : "v"(a), "v"(b), "v"(c));
    return d;
#endif
}

// |w_hh| <= 1/16 exactly -> fixed scale: q = rint(w * 127/0.0625)
__device__ __forceinline__ uint32_t packw4_(const float4 v) {
    int a = __float2int_rn(v.x * 2032.0f);
    int b = __float2int_rn(v.y * 2032.0f);
    int c = __float2int_rn(v.z * 2032.0f);
    int d = __float2int_rn(v.w * 2032.0f);
    return (uint32_t)(a & 255) | ((uint32_t)(b & 255) << 8) |
           ((uint32_t)(c & 255) << 16) | ((uint32_t)(d & 255) << 24);
}

// 8 named scalar weight dwords (32 int8 weights) per group; 8 groups per gate.
#define LWG(pref, G, P, B) \
    uint32_t pref##G##0 = packw4_((P)[(B) + 0]), \
             pref##G##1 = packw4_((P)[(B) + 1]), \
             pref##G##2 = packw4_((P)[(B) + 2]), \
             pref##G##3 = packw4_((P)[(B) + 3]), \
             pref##G##4 = packw4_((P)[(B) + 4]), \
             pref##G##5 = packw4_((P)[(B) + 5]), \
             pref##G##6 = packw4_((P)[(B) + 6]), \
             pref##G##7 = packw4_((P)[(B) + 7]);

// VGPR pin (gate r) and AGPR pin (gates z,n).
// R11 evidence: the RA AGPR-spills most weights and memory-spills the last
// ~15/thread -> 479 MB FETCH and ~1400 cyc/event of HBM latency. "+a" makes
// the z/n residency explicit and guaranteed; in-loop re-pins stop the
// per-use v_accvgpr_read copies from being hoisted into long live ranges.
#define PINV8(pref, G) asm volatile("" : \
    "+v"(pref##G##0), "+v"(pref##G##1), "+v"(pref##G##2), "+v"(pref##G##3), \
    "+v"(pref##G##4), "+v"(pref##G##5), "+v"(pref##G##6), "+v"(pref##G##7));
#define PINA8(pref, G) asm volatile("" : \
    "+a"(pref##G##0), "+a"(pref##G##1), "+a"(pref##G##2), "+a"(pref##G##3), \
    "+a"(pref##G##4), "+a"(pref##G##5), "+a"(pref##G##6), "+a"(pref##G##7));

// single-quad dot groups: only 4 transient h-dwords live at a time
#define DQ1(G, Q) \
    ar = sdot4_(r##G##0, (Q).x, ar); ar = sdot4_(r##G##1, (Q).y, ar); \
    ar = sdot4_(r##G##2, (Q).z, ar); ar = sdot4_(r##G##3, (Q).w, ar); \
    az = sdot4_(z##G##0, (Q).x, az); az = sdot4_(z##G##1, (Q).y, az); \
    az = sdot4_(z##G##2, (Q).z, az); az = sdot4_(z##G##3, (Q).w, az); \
    an = sdot4_(n##G##0, (Q).x, an); an = sdot4_(n##G##1, (Q).y, an); \
    an = sdot4_(n##G##2, (Q).z, an); an = sdot4_(n##G##3, (Q).w, an);
#define DQ2(G, Q) \
    ar = sdot4_(r##G##4, (Q).x, ar); ar = sdot4_(r##G##5, (Q).y, ar); \
    ar = sdot4_(r##G##6, (Q).z, ar); ar = sdot4_(r##G##7, (Q).w, ar); \
    az = sdot4_(z##G##4, (Q).x, az); az = sdot4_(z##G##5, (Q).y, az); \
    az = sdot4_(z##G##6, (Q).z, az); az = sdot4_(z##G##7, (Q).w, az); \
    an = sdot4_(n##G##4, (Q).x, an); an = sdot4_(n##G##5, (Q).y, an); \
    an = sdot4_(n##G##6, (Q).z, an); an = sdot4_(n##G##7, (Q).w, an);

// One block, 256 threads = 4 waves = 1 wave/SIMD. Thread ri owns full GRU
// rows {ri,256+ri,512+ri} int8: r-gate 64 dw in VGPRs, z/n 128 dw in AGPRs.
// VGPR live set ~91 (audited) well under the granted 132; AGPR 128 < 256.
// Per-row f32 constants in LDS tables (read after the dots); uniform scalar
// state in SGPRs via readfirstlane. h int8 in double-buffered LDS; x in LDS.
__global__ __launch_bounds__(256, 1)
void aether_gru_kernel(const float* __restrict__ xg,
                       const float* __restrict__ wih,
                       const float* __restrict__ whh,
                       const float* __restrict__ bih,
                       const float* __restrict__ bhh,
                       const float* __restrict__ wfc,
                       const float* __restrict__ bfc,
                       float* __restrict__ out) {
    const int tid  = threadIdx.x;
    const int lane = tid & 63;
    const int wv   = tid >> 6;              // wave 0..3
    const int ri   = tid;                   // result row 0..255

    __shared__ float xlds[T_STEPS + 2];
    __shared__ __align__(16) signed char hbuf[2][HDIM];
    __shared__ float pp[2][4];
    __shared__ float4 cA[HDIM], cB[HDIM], cC[HDIM];  // per-row constants

    // ---- stage x into LDS (coalesced float4) ----
    {
        const float4* xs4 = (const float4*)xg;
        float4* xd4 = (float4*)xlds;
        #pragma unroll 4
        for (int j = 0; j < T_STEPS / 4 / 256; ++j)
            xd4[tid + 256 * j] = xs4[tid + 256 * j];
        if (tid == 0) { xlds[T_STEPS] = 0.0f; xlds[T_STEPS + 1] = 0.0f; }
    }

    // ---- per-row constants -> LDS tables (13 floats/row, one-time) ----
    {
        const int g0 = tid, g1 = HDIM + tid, g2 = 2 * HDIM + tid;
        cA[tid] = make_float4(wih[2 * g0], wih[2 * g0 + 1],
                              wih[2 * g1], wih[2 * g1 + 1]);
        cB[tid] = make_float4(wih[2 * g2], wih[2 * g2 + 1],
                              bih[g0] + bhh[g0], bih[g1] + bhh[g1]);
        cC[tid] = make_float4(bih[g2], bhh[g2], wfc[tid], 0.0f);
        hbuf[0][tid] = (signed char)0;
    }

    // ---- weights: 3 gates x 64 int8-quad dwords, named scalars ----
    const float4* pr = (const float4*)(whh + (size_t)ri * HDIM);
    const float4* pz = (const float4*)(whh + (size_t)(HDIM + ri) * HDIM);
    const float4* pn = (const float4*)(whh + (size_t)(2 * HDIM + ri) * HDIM);
    LWG(r,A,pr,0)  LWG(r,B,pr,8)  LWG(r,C,pr,16) LWG(r,D,pr,24)
    LWG(r,E,pr,32) LWG(r,F,pr,40) LWG(r,G,pr,48) LWG(r,H,pr,56)
    LWG(z,A,pz,0)  LWG(z,B,pz,8)  LWG(z,C,pz,16) LWG(z,D,pz,24)
    LWG(z,E,pz,32) LWG(z,F,pz,40) LWG(z,G,pz,48) LWG(z,H,pz,56)
    LWG(n,A,pn,0)  LWG(n,B,pn,8)  LWG(n,C,pn,16) LWG(n,D,pn,24)
    LWG(n,E,pn,32) LWG(n,F,pn,40) LWG(n,G,pn,48) LWG(n,H,pn,56)

    // establish residency: r -> VGPRs, z/n -> AGPRs
    PINV8(r,A) PINV8(r,B) PINV8(r,C) PINV8(r,D)
    PINV8(r,E) PINV8(r,F) PINV8(r,G) PINV8(r,H)
    PINA8(z,A) PINA8(z,B) PINA8(z,C) PINA8(z,D)
    PINA8(z,E) PINA8(z,F) PINA8(z,G) PINA8(z,H)
    PINA8(n,A) PINA8(n,B) PINA8(n,C) PINA8(n,D)
    PINA8(n,E) PINA8(n,F) PINA8(n,G) PINA8(n,H)

    const float bf = bfc[0];                 // uniform -> SGPR
    const float WSCALE = 0.0625f / 16129.0f; // (1/16/127) * (1/127)

    __syncthreads();

    // ---- sequential state: uniform -> SGPRs via readfirstlane ----
    float hprev    = 0.0f;                  // per-row (VGPR)
    float xc       = rfl_(xlds[0]);
    float xn       = rfl_(xlds[1]);
    float last_val = rfl_(xc + 1.24f);      // xs[0] + (2*THRESHOLD + 1.0)
    float last_t   = 0.0f;
    int   cnt      = 0;
    int   cur      = 0;                     // hbuf read index
    int   pe       = 0;                     // pp parity
    float cur_pred = 0.0f;

    float* recon = out;
    float* idxp  = out + T_STEPS + 1;

    for (int t = 0; t < T_STEPS; ++t) {
        float xf = rfl_(xlds[t + 2]);                // LDS prefetch, 2 ahead
        const bool ev = fabsf(xc - last_val) >= 0.12f;

        if (ev) {
            // in-loop AGPR re-pin: keeps z/n in AGPRs and blocks hoisting of
            // the per-use accvgpr_read copies (empty asm -> zero instructions)
            PINA8(z,A) PINA8(z,B) PINA8(z,C) PINA8(z,D)
            PINA8(z,E) PINA8(z,F) PINA8(z,G) PINA8(z,H)
            PINA8(n,A) PINA8(n,B) PINA8(n,C) PINA8(n,D)
            PINA8(n,E) PINA8(n,F) PINA8(n,G) PINA8(n,H)

            const float tf = (float)t;
            const float dtv = (tf - last_t) * 0.01f;

            int ar = 0, az = 0, an = 0;
            const uint4* hb = (const uint4*)(&hbuf[cur][0]);
            { uint4 q = hb[0];  DQ1(A, q) } { uint4 q = hb[1];  DQ2(A, q) }
            { uint4 q = hb[2];  DQ1(B, q) } { uint4 q = hb[3];  DQ2(B, q) }
            { uint4 q = hb[4];  DQ1(C, q) } { uint4 q = hb[5];  DQ2(C, q) }
            { uint4 q = hb[6];  DQ1(D, q) } { uint4 q = hb[7];  DQ2(D, q) }
            { uint4 q = hb[8];  DQ1(E, q) } { uint4 q = hb[9];  DQ2(E, q) }
            { uint4 q = hb[10]; DQ1(F, q) } { uint4 q = hb[11]; DQ2(F, q) }
            { uint4 q = hb[12]; DQ1(G, q) } { uint4 q = hb[13]; DQ2(G, q) }
            { uint4 q = hb[14]; DQ1(H, q) } { uint4 q = hb[15]; DQ2(H, q) }

            // per-row constants now (h-quad transients dead)
            const float4 ca  = cA[ri];
            const float4 cbv = cB[ri];
            const float4 cc  = cC[ri];
            const float gir = fmaf(ca.x,  xc, fmaf(ca.y,  dtv, cbv.z));
            const float giz = fmaf(ca.z,  xc, fmaf(ca.w,  dtv, cbv.w));
            const float gin = fmaf(cbv.x, xc, fmaf(cbv.y, dtv, cc.x));

            const float r = sigmoidf_(fmaf((float)ar, WSCALE, gir));
            const float z = sigmoidf_(fmaf((float)az, WSCALE, giz));
            const float hn = fmaf((float)an, WSCALE, cc.y);
            const float n = tanhf_(fmaf(r, hn, gin));
            const float hnew = fmaf(z, hprev, (1.0f - z) * n);
            hprev = hnew;

            // quantize h for next event's dot (|h| < 1 strictly)
            hbuf[cur ^ 1][ri] = (signed char)__float2int_rn(hnew * 127.0f);

            // fc partial: full-wave reduce 64 -> lane 0
            float pv = hnew * cc.z;
            pv += __shfl_down(pv, 32);
            pv += __shfl_down(pv, 16);
            pv += __shfl_down(pv, 8);
            pv += __shfl_down(pv, 4);
            pv += __shfl_down(pv, 2);
            pv += __shfl_down(pv, 1);
            if (lane == 0) pp[pe][wv] = pv;
            if (tid == 0) idxp[cnt] = tf;            // ascending -> sorted

            last_val = xc;
            last_t   = rfl_(tf);
            cnt++;

            __syncthreads();                          // publish hbuf + pp
            cur ^= 1;
            if (tid == 0) {
                const float* q = &pp[pe][0];
                cur_pred = (q[0] + q[1]) + (q[2] + q[3]) + bf;
            }
            pe ^= 1;
        }

        if (tid == 0) recon[t] = cur_pred;            // piecewise-constant pred
        xc = xn; xn = xf;
    }

    if (tid == 0) out[T_STEPS] = (float)cnt;          // n_events
    for (int j = cnt + tid; j < T_STEPS; j += 256)
        idxp[j] = 32768.0f;                           // pad with T
}

extern "C" void kernel_launch(void* const* d_in, const int* in_sizes, int n_in,
                              void* d_out, int out_size, void* d_ws, size_t ws_size,
                              hipStream_t stream) {
    const float* x    = (const float*)d_in[0];
    const float* wih  = (const float*)d_in[1];
    const float* whh  = (const float*)d_in[2];
    const float* bih  = (const float*)d_in[3];
    const float* bhh  = (const float*)d_in[4];
    const float* wfc  = (const float*)d_in[5];
    const float* bfc  = (const float*)d_in[6];
    float* out = (float*)d_out;

    hipLaunchKernelGGL(aether_gru_kernel, dim3(1), dim3(256), 0, stream,
                       x, wih, whh, bih, bhh, wfc, bfc, out);
}

// Round 13
// 32793.994 us; speedup vs baseline: 1.1168x; 1.1168x over previous
//
#include <hip/hip_runtime.h>
#include <stdint.h>
#include <stddef.h>

#define T_STEPS 32768
#define HDIM    256

__device__ __forceinline__ float sigmoidf_(float x) {
    return 1.0f / (1.0f + __expf(-x));
}
__device__ __forceinline__ float tanhf_(float x) {
    float e2 = __expf(2.0f * x);
    return 1.0f - 2.0f / (e2 + 1.0f);
}
// uniform value -> SGPR
__device__ __forceinline__ float rfl_(float x) {
    return __builtin_bit_cast(float, __builtin_amdgcn_readfirstlane(__builtin_bit_cast(int, x)));
}

__device__ __forceinline__ int sdot4_(uint32_t a, uint32_t b, int c) {
#if defined(__has_builtin) && __has_builtin(__builtin_amdgcn_sdot4)
    return __builtin_amdgcn_sdot4((int)a, (int)b, c, false);
#else
    int d;
    asm("v_dot4_i32_i8 %0, %1, %2, %3" : "=v"(d) : "v"(a), "v"(b), "v"(c));
    return d;
#endif
}

// |w_hh| <= 1/16 exactly -> fixed scale: q = rint(w * 127/0.0625)
__device__ __forceinline__ uint32_t packw4_(const float4 v) {
    int a = __float2int_rn(v.x * 2032.0f);
    int b = __float2int_rn(v.y * 2032.0f);
    int c = __float2int_rn(v.z * 2032.0f);
    int d = __float2int_rn(v.w * 2032.0f);
    return (uint32_t)(a & 255) | ((uint32_t)(b & 255) << 8) |
           ((uint32_t)(c & 255) << 16) | ((uint32_t)(d & 255) << 24);
}

// 4 named scalar weight dwords (16 int8 weights) per group; 8 groups/gate.
#define LWG4(pref, G, P, B) \
    uint32_t pref##G##0 = packw4_((P)[(B) + 0]), \
             pref##G##1 = packw4_((P)[(B) + 1]), \
             pref##G##2 = packw4_((P)[(B) + 2]), \
             pref##G##3 = packw4_((P)[(B) + 3]);

// ONE-TIME pre-loop pin: asm output is a fresh opaque def -> the scheduler
// cannot rematerialize the global load in-loop (R10's failure at 96 dw).
// NO in-loop re-pins (R7/R12's failure: per-event redefinition churn).
#define PIN4(pref, G) asm volatile("" : \
    "+v"(pref##G##0), "+v"(pref##G##1), "+v"(pref##G##2), "+v"(pref##G##3));

// 12 sdot4 consuming ONE 16-byte h-quad (16 int8 h) for all 3 gates:
// transient pressure = 4 dwords only.
#define DQ(G, Q) \
    ar = sdot4_(r##G##0, (Q).x, ar); ar = sdot4_(r##G##1, (Q).y, ar); \
    ar = sdot4_(r##G##2, (Q).z, ar); ar = sdot4_(r##G##3, (Q).w, ar); \
    az = sdot4_(z##G##0, (Q).x, az); az = sdot4_(z##G##1, (Q).y, az); \
    az = sdot4_(z##G##2, (Q).z, az); az = sdot4_(z##G##3, (Q).w, az); \
    an = sdot4_(n##G##0, (Q).x, an); an = sdot4_(n##G##1, (Q).y, an); \
    an = sdot4_(n##G##2, (Q).z, an); an = sdot4_(n##G##3, (Q).w, an);

// One block, 512 threads = 8 waves = 2 waves/SIMD (empirical VGPR cap: 128).
// R13 = FIT (96 weight dwords/thread, audited live set ~123 <= 128) + PIN
// (one-time, blocks remat) simultaneously — every prior round had only one.
// Thread (wave wv, lane l): column-half hq=l>>5, row ri=wv*32+(l&31); owns
// rows {ri,256+ri,512+ri} x 128 cols as 3x32 named int8-quad dwords
// (v_dot4_i32_i8). Halves combined with one int shfl_down(32) per gate.
// Per-row f32 constants in LDS float4 tables, read AFTER the dots; uniform
// scalar state in SGPRs via readfirstlane. h int8 in double-buffered LDS;
// x staged in LDS. Event logic exact f32; matvec int8 (absmax 9.8e-4).
__global__ __launch_bounds__(512, 1)
void aether_gru_kernel(const float* __restrict__ xg,
                       const float* __restrict__ wih,
                       const float* __restrict__ whh,
                       const float* __restrict__ bih,
                       const float* __restrict__ bhh,
                       const float* __restrict__ wfc,
                       const float* __restrict__ bfc,
                       float* __restrict__ out) {
    const int tid  = threadIdx.x;
    const int lane = tid & 63;
    const int wv   = tid >> 6;              // wave 0..7
    const int hq   = lane >> 5;             // column half 0/1
    const int ri   = wv * 32 + (lane & 31); // result row 0..255

    __shared__ float xlds[T_STEPS + 2];
    __shared__ __align__(16) signed char hbuf[2][HDIM];
    __shared__ float pp[2][8];
    __shared__ float4 cA[HDIM], cB[HDIM], cC[HDIM];  // per-row constants

    // ---- stage x into LDS (coalesced float4) ----
    {
        const float4* xs4 = (const float4*)xg;
        float4* xd4 = (float4*)xlds;
        #pragma unroll 4
        for (int j = 0; j < T_STEPS / 4 / 512; ++j)
            xd4[tid + 512 * j] = xs4[tid + 512 * j];
        if (tid == 0) { xlds[T_STEPS] = 0.0f; xlds[T_STEPS + 1] = 0.0f; }
    }

    // ---- per-row constants -> LDS tables (13 floats/row, one-time) ----
    if (tid < HDIM) {
        const int g0 = tid, g1 = HDIM + tid, g2 = 2 * HDIM + tid;
        cA[tid] = make_float4(wih[2 * g0], wih[2 * g0 + 1],
                              wih[2 * g1], wih[2 * g1 + 1]);
        cB[tid] = make_float4(wih[2 * g2], wih[2 * g2 + 1],
                              bih[g0] + bhh[g0], bih[g1] + bhh[g1]);
        cC[tid] = make_float4(bih[g2], bhh[g2], wfc[tid], 0.0f);
        hbuf[0][tid] = (signed char)0;
    }

    // ---- weights: 3 gates x 8 groups x 4 dwords (this thread's half) ----
    const float4* pr = (const float4*)(whh + (size_t)ri * HDIM);
    const float4* pz = (const float4*)(whh + (size_t)(HDIM + ri) * HDIM);
    const float4* pn = (const float4*)(whh + (size_t)(2 * HDIM + ri) * HDIM);
    const int cb = hq * 32;                 // this half's first float4 index
    LWG4(r,A,pr,cb+0)  LWG4(r,B,pr,cb+4)  LWG4(r,C,pr,cb+8)  LWG4(r,D,pr,cb+12)
    LWG4(r,E,pr,cb+16) LWG4(r,F,pr,cb+20) LWG4(r,G,pr,cb+24) LWG4(r,H,pr,cb+28)
    LWG4(z,A,pz,cb+0)  LWG4(z,B,pz,cb+4)  LWG4(z,C,pz,cb+8)  LWG4(z,D,pz,cb+12)
    LWG4(z,E,pz,cb+16) LWG4(z,F,pz,cb+20) LWG4(z,G,pz,cb+24) LWG4(z,H,pz,cb+28)
    LWG4(n,A,pn,cb+0)  LWG4(n,B,pn,cb+4)  LWG4(n,C,pn,cb+8)  LWG4(n,D,pn,cb+12)
    LWG4(n,E,pn,cb+16) LWG4(n,F,pn,cb+20) LWG4(n,G,pn,cb+24) LWG4(n,H,pn,cb+28)

    // one-time residency pins (pre-loop ONLY)
    PIN4(r,A) PIN4(r,B) PIN4(r,C) PIN4(r,D)
    PIN4(r,E) PIN4(r,F) PIN4(r,G) PIN4(r,H)
    PIN4(z,A) PIN4(z,B) PIN4(z,C) PIN4(z,D)
    PIN4(z,E) PIN4(z,F) PIN4(z,G) PIN4(z,H)
    PIN4(n,A) PIN4(n,B) PIN4(n,C) PIN4(n,D)
    PIN4(n,E) PIN4(n,F) PIN4(n,G) PIN4(n,H)

    const float bf = bfc[0];                 // uniform -> SGPR
    const float WSCALE = 0.0625f / 16129.0f; // (1/16/127) * (1/127)

    __syncthreads();

    // ---- sequential state: uniform -> SGPRs via readfirstlane ----
    float hprev    = 0.0f;                  // per-row (VGPR)
    float xc       = rfl_(xlds[0]);
    float xn       = rfl_(xlds[1]);
    float last_val = rfl_(xc + 1.24f);      // xs[0] + (2*THRESHOLD + 1.0)
    float last_t   = 0.0f;
    int   cnt      = 0;
    int   cur      = 0;                     // hbuf read index
    int   pe       = 0;                     // pp parity
    float cur_pred = 0.0f;

    float* recon = out;
    float* idxp  = out + T_STEPS + 1;

    for (int t = 0; t < T_STEPS; ++t) {
        float xf = rfl_(xlds[t + 2]);                // LDS prefetch, 2 ahead
        const bool ev = fabsf(xc - last_val) >= 0.12f;

        if (ev) {
            const float tf = (float)t;
            const float dtv = (tf - last_t) * 0.01f;

            int ar = 0, az = 0, an = 0;
            const uint4* hb = (const uint4*)(&hbuf[cur][hq * 128]);
            { uint4 q = hb[0]; DQ(A, q) }
            { uint4 q = hb[1]; DQ(B, q) }
            { uint4 q = hb[2]; DQ(C, q) }
            { uint4 q = hb[3]; DQ(D, q) }
            { uint4 q = hb[4]; DQ(E, q) }
            { uint4 q = hb[5]; DQ(F, q) }
            { uint4 q = hb[6]; DQ(G, q) }
            { uint4 q = hb[7]; DQ(H, q) }

            // combine column-halves: low 32 lanes get full integer sums
            ar += __shfl_down(ar, 32);
            az += __shfl_down(az, 32);
            an += __shfl_down(an, 32);

            // per-row constants now (h-quad transients dead)
            const float4 ca  = cA[ri];
            const float4 cbv = cB[ri];
            const float4 cc  = cC[ri];
            const float gir = fmaf(ca.x,  xc, fmaf(ca.y,  dtv, cbv.z));
            const float giz = fmaf(ca.z,  xc, fmaf(ca.w,  dtv, cbv.w));
            const float gin = fmaf(cbv.x, xc, fmaf(cbv.y, dtv, cc.x));

            const float r = sigmoidf_(fmaf((float)ar, WSCALE, gir));
            const float z = sigmoidf_(fmaf((float)az, WSCALE, giz));
            const float hn = fmaf((float)an, WSCALE, cc.y);
            const float n = tanhf_(fmaf(r, hn, gin));
            const float hnew = fmaf(z, hprev, (1.0f - z) * n);
            hprev = hnew;                            // valid on low-half lanes

            // quantize h for next event's dot (|h| < 1 strictly)
            if (lane < 32)
                hbuf[cur ^ 1][ri] = (signed char)__float2int_rn(hnew * 127.0f);

            // fc partial: zero upper half, reduce 32 -> lane 0
            float pv = (lane < 32) ? hnew * cc.z : 0.0f;
            pv += __shfl_down(pv, 16);
            pv += __shfl_down(pv, 8);
            pv += __shfl_down(pv, 4);
            pv += __shfl_down(pv, 2);
            pv += __shfl_down(pv, 1);
            if (lane == 0) pp[pe][wv] = pv;
            if (tid == 0) idxp[cnt] = tf;            // ascending -> sorted

            last_val = xc;
            last_t   = rfl_(tf);
            cnt++;

            __syncthreads();                          // publish hbuf + pp
            cur ^= 1;
            if (tid == 0) {
                const float* q = &pp[pe][0];
                cur_pred = ((q[0] + q[1]) + (q[2] + q[3]))
                         + ((q[4] + q[5]) + (q[6] + q[7])) + bf;
            }
            pe ^= 1;
        }

        if (tid == 0) recon[t] = cur_pred;            // piecewise-constant pred
        xc = xn; xn = xf;
    }

    if (tid == 0) out[T_STEPS] = (float)cnt;          // n_events
    for (int j = cnt + tid; j < T_STEPS; j += 512)
        idxp[j] = 32768.0f;                           // pad with T
}

extern "C" void kernel_launch(void* const* d_in, const int* in_sizes, int n_in,
                              void* d_out, int out_size, void* d_ws, size_t ws_size,
                              hipStream_t stream) {
    const float* x    = (const float*)d_in[0];
    const float* wih  = (const float*)d_in[1];
    const float* whh  = (const float*)d_in[2];
    const float* bih  = (const float*)d_in[3];
    const float* bhh  = (const float*)d_in[4];
    const float* wfc  = (const float*)d_in[5];
    const float* bfc  = (const float*)d_in[6];
    float* out = (float*)d_out;

    hipLaunchKernelGGL(aether_gru_kernel, dim3(1), dim3(512), 0, stream,
                       x, wih, whh, bih, bhh, wfc, bfc, out);
}